// Round 1
// baseline (45.436 us; speedup 1.0000x reference)
//
#include <hip/hip_runtime.h>

// Embedding row gather: out[r, :] = data[idx[r], :]
//   idx  : 65536 x int32   (values in [0, 100000))
//   data : [100000, 512] fp32
//   out  : [65536, 512] fp32
//
// One thread per float4 (16 B) of output. 512 floats/row = 128 float4/row.
// 128 consecutive threads (2 waves) share one index -> idx load is an L1
// broadcast. Row reads are contiguous 2 KB; writes fully coalesced.

#define VEC_PER_ROW 128  // 512 floats / 4

__global__ void gather_rows_kernel(const int* __restrict__ idx,
                                   const float4* __restrict__ data,
                                   float4* __restrict__ out,
                                   long long total_vec4) {
    long long i = (long long)blockIdx.x * blockDim.x + threadIdx.x;
    const long long stride = (long long)gridDim.x * blockDim.x;
    for (; i < total_vec4; i += stride) {
        const int row = (int)(i >> 7);        // i / VEC_PER_ROW
        const int col = (int)(i & (VEC_PER_ROW - 1));
        const int src = idx[row];
        out[i] = data[(long long)src * VEC_PER_ROW + col];
    }
}

extern "C" void kernel_launch(void* const* d_in, const int* in_sizes, int n_in,
                              void* d_out, int out_size, void* d_ws, size_t ws_size,
                              hipStream_t stream) {
    const int*    idx  = (const int*)d_in[0];      // x flattened: 16384*4*1 int32
    const float4* data = (const float4*)d_in[1];   // [100000, 512] fp32
    float4*       out  = (float4*)d_out;           // [65536, 512] fp32

    const long long n_rows     = in_sizes[0];               // 65536
    const long long total_vec4 = n_rows * VEC_PER_ROW;      // 8,388,608

    const int  block  = 256;
    long long  nblk   = (total_vec4 + block - 1) / block;
    const int  grid   = (int)(nblk > 2048 ? 2048 : nblk);   // grid-stride cap

    gather_rows_kernel<<<grid, block, 0, stream>>>(idx, data, out, total_vec4);
}

// Round 3
// 44.549 us; speedup vs baseline: 1.0199x; 1.0199x over previous
//
#include <hip/hip_runtime.h>

// Embedding row gather: out[r, :] = data[idx[r], :]
//   idx  : 65536 x int32   (values in [0, 100000))
//   data : [100000, 512] fp32  (204.8 MB -- nearly L3-resident)
//   out  : [65536, 512] fp32   (134 MB, write-once)
//
// One thread per float4 (16 B) of output. 128 consecutive threads share one
// index -> idx load broadcasts. Row reads contiguous 2 KB, fully coalesced.
// Output stores are NON-TEMPORAL (write-once, never re-read): keep out of
// L2/L3 so the gather table stays cache-resident -> row reads become hits.

typedef float f32x4 __attribute__((ext_vector_type(4)));

#define VEC_PER_ROW 128  // 512 floats / 4

__global__ void gather_rows_kernel(const int* __restrict__ idx,
                                   const f32x4* __restrict__ data,
                                   f32x4* __restrict__ out,
                                   long long total_vec4) {
    long long i = (long long)blockIdx.x * blockDim.x + threadIdx.x;
    const long long stride = (long long)gridDim.x * blockDim.x;
    for (; i < total_vec4; i += stride) {
        const int row = (int)(i >> 7);        // i / VEC_PER_ROW
        const int col = (int)(i & (VEC_PER_ROW - 1));
        const int src = idx[row];
        const f32x4 v = data[(long long)src * VEC_PER_ROW + col];
        __builtin_nontemporal_store(v, &out[i]);
    }
}

extern "C" void kernel_launch(void* const* d_in, const int* in_sizes, int n_in,
                              void* d_out, int out_size, void* d_ws, size_t ws_size,
                              hipStream_t stream) {
    const int*   idx  = (const int*)d_in[0];      // x flattened: 16384*4*1 int32
    const f32x4* data = (const f32x4*)d_in[1];    // [100000, 512] fp32
    f32x4*       out  = (f32x4*)d_out;            // [65536, 512] fp32

    const long long n_rows     = in_sizes[0];               // 65536
    const long long total_vec4 = n_rows * VEC_PER_ROW;      // 8,388,608

    // 2048 blocks x 256 = 8 blocks/CU x 4 waves = 32 waves/CU (full residency)
    const int  block  = 256;
    long long  nblk   = (total_vec4 + block - 1) / block;
    const int  grid   = (int)(nblk > 2048 ? 2048 : nblk);

    gather_rows_kernel<<<grid, block, 0, stream>>>(idx, data, out, total_vec4);
}

// Round 4
// 44.184 us; speedup vs baseline: 1.0283x; 1.0083x over previous
//
#include <hip/hip_runtime.h>

// Embedding row gather: out[r, :] = data[idx[r], :]
//   idx  : 65536 x int32   (values in [0, 100000))
//   data : [100000, 512] fp32  (204.8 MB -- fits 256 MB L3 alone)
//   out  : [65536, 512] fp32   (134 MB, write-once, never re-read)
//
// One thread per float4 (16 B) of output. All 64 lanes of a wave share one
// row index -> idx load broadcasts. Row reads contiguous 2 KB, coalesced.
//
// Output stores use inline-asm `global_store_dwordx4 ... sc0 sc1 nt`:
// system-scope + non-temporal, to write AROUND L2/MALL. Goal: keep the
// read-only table L3-resident across graph replays so gather reads hit L3
// (~34.5 TB/s) and the kernel becomes write-bound (~19 us floor).
// (__builtin_nontemporal_store only sets `nt`, which measurably did NOT
// change MALL allocation: 45.4 -> 44.5 us, R3.)

typedef float f32x4 __attribute__((ext_vector_type(4)));

#define VEC_PER_ROW 128  // 512 floats / 4

__global__ void gather_rows_kernel(const int* __restrict__ idx,
                                   const f32x4* __restrict__ data,
                                   f32x4* __restrict__ out,
                                   long long total_vec4) {
    long long i = (long long)blockIdx.x * blockDim.x + threadIdx.x;
    const long long stride = (long long)gridDim.x * blockDim.x;
    for (; i < total_vec4; i += stride) {
        const int row = (int)(i >> 7);        // i / VEC_PER_ROW
        const int col = (int)(i & (VEC_PER_ROW - 1));
        const int src = idx[row];
        const f32x4 v = data[(long long)src * VEC_PER_ROW + col];
        // write-around store: system-scope, non-temporal
        asm volatile("global_store_dwordx4 %0, %1, off sc0 sc1 nt"
                     :
                     : "v"(&out[i]), "v"(v)
                     : "memory");
    }
}

extern "C" void kernel_launch(void* const* d_in, const int* in_sizes, int n_in,
                              void* d_out, int out_size, void* d_ws, size_t ws_size,
                              hipStream_t stream) {
    const int*   idx  = (const int*)d_in[0];      // x flattened: 16384*4*1 int32
    const f32x4* data = (const f32x4*)d_in[1];    // [100000, 512] fp32
    f32x4*       out  = (f32x4*)d_out;            // [65536, 512] fp32

    const long long n_rows     = in_sizes[0];               // 65536
    const long long total_vec4 = n_rows * VEC_PER_ROW;      // 8,388,608

    // 2048 blocks x 256 = 8 blocks/CU x 4 waves = 32 waves/CU (full residency)
    const int  block  = 256;
    long long  nblk   = (total_vec4 + block - 1) / block;
    const int  grid   = (int)(nblk > 2048 ? 2048 : nblk);

    gather_rows_kernel<<<grid, block, 0, stream>>>(idx, data, out, total_vec4);
}